// Round 8
// baseline (667.145 us; speedup 1.0000x reference)
//
#include <hip/hip_runtime.h>
#include <stdint.h>

#define MDIM 4096
#define NDIM 1024
#define KDIM 512
#define NCH  16        // 16 chunks; each stages 8 k per segment x 4 segments
#define TSTEPS 50

typedef const __attribute__((address_space(1))) void cgv_t;
typedef __attribute__((address_space(3))) void lv_t;

__device__ __forceinline__ void gload16(const float* g, float* s) {
    __builtin_amdgcn_global_load_lds((cgv_t*)g, (lv_t*)s, 16, 0, 0);
}

__global__ __launch_bounds__(256) void zero_tot_kernel(float* __restrict__ tot) {
    int i = blockIdx.x * 256 + threadIdx.x;
    if (i < MDIM) tot[i] = 0.0f;
}

// In-block K-split: 1024 threads = 4 segments x 256; each segment does the
// full 128x128 tile with 8x8 micro over K/4 = 128. -> 8x8's LDS wall
// (8192 b128/CU = 41us) at 4 waves/SIMD (R2-proven exposure ~1.1x).
// Combine partials via LDS in 4 column-quarters, then 50-step LIF recurrence.
__global__ __launch_bounds__(1024, 1) void snn_fused_kernel(
    const float* __restrict__ A,    // x [4096,512]
    const float* __restrict__ B,    // W_proj [512,1024]
    const float* __restrict__ bias, // b_proj [1024]
    float* __restrict__ agg,        // d_out[0 : 4096*1024]
    float* __restrict__ tot)        // d_out[4096*1024 : +4096]
{
    // 64KB union: main loop = sA[2][128][32] + sB[2][32][128];
    // combine = R0,R1 as [128][44] (176B rows: 16B-aligned, 2-way banks max)
    __shared__ __align__(16) float smem[16384];

    const int tid = threadIdx.x;
    const int l   = tid & 63;
    const int w   = tid >> 6;          // wave 0..15
    const int seg = w >> 2;            // k-segment 0..3 (k in [seg*128, +128))
    const int sx  = tid & 15;          // col group within segment grid
    const int ty  = (tid & 255) >> 4;  // row group within segment grid
    const int ty1 = ty & 1;            // A quad-swizzle key (2 quads/chunk)

    // XCD swizzle (bijective, 256 = 8 x 32)
    const int bswz = (blockIdx.x & 7) * 32 + (blockIdx.x >> 3);
    const int m0 = (bswz >> 3) * 128;
    const int n0 = (bswz & 7) * 128;

    // --- staging: 1 A-gload16 + 1 B-gload16 per thread per chunk ---
    // A chunk layout [128 rows][4 seg * 8 k]; slot q holds k-quad (q ^ keyX),
    // keyX = (X>>2)&1, applied on the SOURCE (dest stays linear).
    const int Xs  = 8 * w + (l >> 3);           // A row
    const int ssl = (l & 7) >> 1;               // segment slot
    const int qsl = (l & 1) ^ ((Xs >> 2) & 1);  // inverse-swizzled quad
    const float* srcA = A + (size_t)(m0 + Xs) * KDIM + ssl * 128 + qsl * 4;
    // B chunk layout [32 k-rows][128 cols], kl = seg*8 + within
    const int kl = 2 * w + (l >> 5);
    const float* srcB = B + (size_t)((kl >> 3) * 128 + (kl & 7)) * NDIM
                          + n0 + (l & 31) * 4;

#define STAGE(buf, ch) do {                                                   \
    gload16(srcA + (ch) * 8,                smem + (buf) * 4096 + w * 256);   \
    gload16(srcB + (size_t)(ch) * 8 * NDIM, smem + 8192 + (buf) * 4096 + w * 256); \
} while (0)

// one k-quad (4 k): A 8 b128 (8 rows, 16-lane bcast, 2-way), B 8 b128 (2-way)
#define LOADQ(j, aR, bR) do {                                                 \
    const float* pa_ = lA + (((j) ^ ty1) & 1) * 4;                            \
    _Pragma("unroll") for (int r_ = 0; r_ < 4; ++r_) {                        \
        float4 v_ = *(const float4*)(pa_ + r_ * 32);                          \
        aR[r_][0] = v_.x; aR[r_][1] = v_.y; aR[r_][2] = v_.z; aR[r_][3] = v_.w; \
        float4 u_ = *(const float4*)(pa_ + 2048 + r_ * 32);                   \
        aR[4+r_][0] = u_.x; aR[4+r_][1] = u_.y; aR[4+r_][2] = u_.z; aR[4+r_][3] = u_.w; \
    }                                                                         \
    const float* pb_ = lB + (j) * 512;                                        \
    _Pragma("unroll") for (int k_ = 0; k_ < 4; ++k_) {                        \
        float4 v_ = *(const float4*)(pb_ + k_ * 128);                         \
        bR[k_][0] = v_.x; bR[k_][1] = v_.y; bR[k_][2] = v_.z; bR[k_][3] = v_.w; \
        float4 u_ = *(const float4*)(pb_ + k_ * 128 + 64);                    \
        bR[k_][4] = u_.x; bR[k_][5] = u_.y; bR[k_][6] = u_.z; bR[k_][7] = u_.w; \
    }                                                                         \
} while (0)

#define FMAQ(aR, bR) do {                                                     \
    _Pragma("unroll") for (int kk_ = 0; kk_ < 4; ++kk_)                       \
        _Pragma("unroll") for (int r_ = 0; r_ < 8; ++r_)                      \
            _Pragma("unroll") for (int c_ = 0; c_ < 8; ++c_)                  \
                acc[r_][c_] = fmaf(aR[r_][kk_], bR[kk_][c_], acc[r_][c_]);    \
} while (0)

    STAGE(0, 0);
    STAGE(1, 1);

    float acc[8][8];
    #pragma unroll
    for (int r = 0; r < 8; ++r)
        #pragma unroll
        for (int c = 0; c < 8; ++c) acc[r][c] = 0.0f;

    #pragma unroll 1
    for (int ch = 0; ch < NCH; ++ch) {
        if (ch < NCH - 1) asm volatile("s_waitcnt vmcnt(2)" ::: "memory");
        else              asm volatile("s_waitcnt vmcnt(0)" ::: "memory");
        __builtin_amdgcn_s_barrier();
        asm volatile("" ::: "memory");
        const float* lA = smem + (ch & 1) * 4096 + ty * 128 + seg * 8;
        const float* lB = smem + 8192 + (ch & 1) * 4096 + seg * 1024 + sx * 4;
        {
            float a0[8][4], b0[4][8];
            LOADQ(0, a0, b0);
            FMAQ(a0, b0);
        }
        {
            float a1[8][4], b1[4][8];
            LOADQ(1, a1, b1);
            FMAQ(a1, b1);
        }
        __builtin_amdgcn_s_barrier();
        asm volatile("" ::: "memory");
        if (ch + 2 < NCH) STAGE(ch & 1, ch + 2);
    }

    // ---- combine 4 partial sums + recurrence, in 4 column-quarters ----
    float* R0 = smem;              // [128][44]
    float* R1 = smem + 5632;       // [128][44]
    const int row4 = tid >> 3;     // step-4 ownership: 1 row x 4 cols/quarter
    const int f4   = tid & 7;
    int rs = 0;                    // spike-count row partial (this thread)

    #pragma unroll
    for (int Q = 0; Q < 4; ++Q) {
        const int h    = Q >> 1;                 // which acc col-half
        const bool sxin = ((sx >> 3) == (Q & 1));
        // step 1: segments 2,3 deposit their quarter-partials
        if (seg == 2 && sxin) {
            #pragma unroll
            for (int r = 0; r < 8; ++r) {
                const int row = ((r >> 2) << 6) + ty * 4 + (r & 3);
                float4 v = make_float4(acc[r][h*4+0], acc[r][h*4+1],
                                       acc[r][h*4+2], acc[r][h*4+3]);
                *(float4*)&R0[row * 44 + (sx & 7) * 4] = v;
            }
        }
        if (seg == 3 && sxin) {
            #pragma unroll
            for (int r = 0; r < 8; ++r) {
                const int row = ((r >> 2) << 6) + ty * 4 + (r & 3);
                float4 v = make_float4(acc[r][h*4+0], acc[r][h*4+1],
                                       acc[r][h*4+2], acc[r][h*4+3]);
                *(float4*)&R1[row * 44 + (sx & 7) * 4] = v;
            }
        }
        __syncthreads();
        // step 2: segments 0,1 accumulate them
        if (seg == 0 && sxin) {
            #pragma unroll
            for (int r = 0; r < 8; ++r) {
                const int row = ((r >> 2) << 6) + ty * 4 + (r & 3);
                float4 v = *(const float4*)&R0[row * 44 + (sx & 7) * 4];
                acc[r][h*4+0] += v.x; acc[r][h*4+1] += v.y;
                acc[r][h*4+2] += v.z; acc[r][h*4+3] += v.w;
            }
        }
        if (seg == 1 && sxin) {
            #pragma unroll
            for (int r = 0; r < 8; ++r) {
                const int row = ((r >> 2) << 6) + ty * 4 + (r & 3);
                float4 v = *(const float4*)&R1[row * 44 + (sx & 7) * 4];
                acc[r][h*4+0] += v.x; acc[r][h*4+1] += v.y;
                acc[r][h*4+2] += v.z; acc[r][h*4+3] += v.w;
            }
        }
        __syncthreads();
        // step 3: half-sums (s0+s2 -> R0, s1+s3 -> R1)
        if ((seg == 0 || seg == 1) && sxin) {
            float* Rd = (seg == 0) ? R0 : R1;
            #pragma unroll
            for (int r = 0; r < 8; ++r) {
                const int row = ((r >> 2) << 6) + ty * 4 + (r & 3);
                float4 v = make_float4(acc[r][h*4+0], acc[r][h*4+1],
                                       acc[r][h*4+2], acc[r][h*4+3]);
                *(float4*)&Rd[row * 44 + (sx & 7) * 4] = v;
            }
        }
        __syncthreads();
        // step 4: all 1024 threads -> full sums + bias + 50-step LIF on 4 elems
        {
            float4 v0 = *(const float4*)&R0[row4 * 44 + f4 * 4];
            float4 v1 = *(const float4*)&R1[row4 * 44 + f4 * 4];
            float4 bb = *(const float4*)(bias + n0 + Q * 32 + f4 * 4);
            float c[4]  = {v0.x + v1.x + bb.x, v0.y + v1.y + bb.y,
                           v0.z + v1.z + bb.z, v0.w + v1.w + bb.w};
            float c1[4], mem[4];
            int cnt[4];
            bool sp[4];
            #pragma unroll
            for (int j = 0; j < 4; ++j) {
                c1[j] = c[j] - 1.0f; mem[j] = 0.0f; cnt[j] = 0; sp[j] = false;
            }
            // both LIF layers identical -> simulate once; spk_t == reset_{t+1}
            #pragma unroll 1
            for (int t = 0; t < TSTEPS; ++t) {
                #pragma unroll
                for (int j = 0; j < 4; ++j) {
                    mem[j] = fmaf(0.95f, mem[j], sp[j] ? c1[j] : c[j]);
                    sp[j]  = mem[j] > 1.0f;
                    cnt[j] += sp[j] ? 1 : 0;
                }
            }
            float4 o = make_float4((float)cnt[0], (float)cnt[1],
                                   (float)cnt[2], (float)cnt[3]);
            *(float4*)&agg[(size_t)(m0 + row4) * NDIM + n0 + Q * 32 + f4 * 4] = o;
            rs += cnt[0] + cnt[1] + cnt[2] + cnt[3];
        }
        __syncthreads();   // R0/R1 reused by next quarter
    }

    // tot: integer counts, exact in fp32, order-independent atomics
    rs += __shfl_xor(rs, 1);
    rs += __shfl_xor(rs, 2);
    rs += __shfl_xor(rs, 4);
    if (f4 == 0) atomicAdd(&tot[m0 + row4], 2.0f * (float)rs);
}

extern "C" void kernel_launch(void* const* d_in, const int* in_sizes, int n_in,
                              void* d_out, int out_size, void* d_ws, size_t ws_size,
                              hipStream_t stream) {
    const float* x = (const float*)d_in[0];
    const float* W = (const float*)d_in[1];
    const float* b = (const float*)d_in[2];
    float* agg = (float*)d_out;
    float* tot = agg + (size_t)MDIM * NDIM;

    zero_tot_kernel<<<(MDIM + 255) / 256, 256, 0, stream>>>(tot);
    snn_fused_kernel<<<(MDIM / 128) * (NDIM / 128), 1024, 0, stream>>>(x, W, b, agg, tot);
}

// Round 9
// 96.419 us; speedup vs baseline: 6.9192x; 6.9192x over previous
//
#include <hip/hip_runtime.h>
#include <stdint.h>

#define MDIM 4096
#define NDIM 1024
#define KDIM 512
#define TSTEPS 50
#define NCH 24            // 3 split-segments x 8 chunks of BK=64

typedef _Float16 half8  __attribute__((ext_vector_type(8)));
typedef _Float16 half4  __attribute__((ext_vector_type(4)));
typedef _Float16 half2v __attribute__((ext_vector_type(2)));
typedef float    f32x4  __attribute__((ext_vector_type(4)));

__global__ __launch_bounds__(256) void zero_tot_kernel(float* __restrict__ tot) {
    int i = blockIdx.x * 256 + threadIdx.x;
    if (i < MDIM) tot[i] = 0.0f;
}

// Pre-split + transpose W: B1[n][k] = f16(W), B2[n][k] = f16((W - B1)*2048).
// Scaling keeps residuals in f16-normal range (no denorm-flush hazard).
__global__ __launch_bounds__(256) void bsplit_kernel(
    const float* __restrict__ B, _Float16* __restrict__ B1, _Float16* __restrict__ B2)
{
    int idx = blockIdx.x * 256 + threadIdx.x;   // 262144 = 1024 n x 256 k-pairs
    int n  = idx & 1023;
    int k2 = idx >> 10;
    float v0 = B[(size_t)(2 * k2) * NDIM + n];
    float v1 = B[(size_t)(2 * k2 + 1) * NDIM + n];
    _Float16 h0 = (_Float16)v0, h1 = (_Float16)v1;
    _Float16 r0 = (_Float16)((v0 - (float)h0) * 2048.0f);
    _Float16 r1 = (_Float16)((v1 - (float)h1) * 2048.0f);
    half2v a = {h0, h1}, r = {r0, r1};
    *(half2v*)(B1 + (size_t)n * KDIM + 2 * k2) = a;
    *(half2v*)(B2 + (size_t)n * KDIM + 2 * k2) = r;
}

// Split-2 f16 MFMA GEMM (3 passes folded into one K'=1536 loop) + fused LIF.
// Segments: ch 0-7: a2s*b1 ; ch 8-15: a1*b2s ; [acc *= 2^-11] ; ch 16-23: a1*b1.
// 256 thr (4 waves), 128x128 tile, wave owns 64x64 = 4x4 frags of 16x16x32.
// LDS: sA[row][k] & sB[n][k], both XOR-swizzled (byte ^= (row&7)<<4) on write
// AND read (reg-staged, so both sides controlled). A/B frags use the same
// (lanegroup,elem)->k map -> correct for any HW-internal k-order (positional
// operand pairing); C/D layout = m89-verified col=lane&15,row=(lane>>4)*4+reg.
__global__ __launch_bounds__(256, 1) void snn_mfma_kernel(
    const float*    __restrict__ A,
    const _Float16* __restrict__ B1,
    const _Float16* __restrict__ B2,
    const float*    __restrict__ bias,
    float*          __restrict__ agg,
    float*          __restrict__ tot)
{
    __shared__ __align__(16) unsigned char lds[2][32768];  // per buf: A 16KB | B 16KB

    const int t  = threadIdx.x;
    const int l  = t & 63;
    const int w  = t >> 6;
    const int qr = (w >> 1) * 64;   // wave output quadrant
    const int qc = (w & 1) * 64;
    const int lg = l >> 4;          // k-group 0..3
    const int li = l & 15;

    // XCD swizzle (bijective, 256 = 8 x 32)
    const int swz = (blockIdx.x & 7) * 32 + (blockIdx.x >> 3);
    const int m0 = (swz >> 3) * 128;
    const int n0 = (swz & 7) * 128;

    // staging maps: A per q(0..7): row=q*16+(t>>4), pos=t&15 (float4, coalesced)
    //               B per q(0..3): n  =q*32+(t>>3), pos=t&7  (half8,  coalesced)
    const int arow = t >> 4, apos = t & 15;
    const int bn   = t >> 3, bpos = t & 7;

    float4 pa[8];
    half8  pb[4];

#define GLOAD(ch) do {                                                        \
    const int seg_ = (ch) >> 3, k0_ = ((ch) & 7) * 64;                        \
    _Pragma("unroll") for (int q_ = 0; q_ < 8; ++q_)                          \
        pa[q_] = *(const float4*)(A + (size_t)(m0 + q_ * 16 + arow) * KDIM    \
                                    + k0_ + apos * 4);                        \
    const _Float16* bs_ = (seg_ == 1) ? B2 : B1;                              \
    _Pragma("unroll") for (int q_ = 0; q_ < 4; ++q_)                          \
        pb[q_] = *(const half8*)(bs_ + (size_t)(n0 + q_ * 32 + bn) * KDIM     \
                                     + k0_ + bpos * 8);                       \
} while (0)

#define LWRITE(buf, ch) do {                                                  \
    const int seg_ = (ch) >> 3;                                               \
    unsigned char* sA_ = &lds[buf][0];                                        \
    unsigned char* sB_ = &lds[buf][16384];                                    \
    _Pragma("unroll") for (int q_ = 0; q_ < 8; ++q_) {                        \
        const int row_ = q_ * 16 + arow;                                      \
        const float* pv_ = (const float*)&pa[q_];                             \
        half4 h_;                                                             \
        if (seg_ == 0) {                                                      \
            _Pragma("unroll") for (int e_ = 0; e_ < 4; ++e_) {                \
                _Float16 h1_ = (_Float16)pv_[e_];                             \
                h_[e_] = (_Float16)((pv_[e_] - (float)h1_) * 2048.0f);        \
            }                                                                 \
        } else {                                                              \
            _Pragma("unroll") for (int e_ = 0; e_ < 4; ++e_)                  \
                h_[e_] = (_Float16)pv_[e_];                                   \
        }                                                                     \
        *(half4*)(sA_ + row_ * 128 + ((apos * 8) ^ ((row_ & 7) << 4))) = h_;  \
    }                                                                         \
    _Pragma("unroll") for (int q_ = 0; q_ < 4; ++q_) {                        \
        const int n_ = q_ * 32 + bn;                                          \
        *(half8*)(sB_ + n_ * 128 + ((bpos * 16) ^ ((n_ & 7) << 4))) = pb[q_]; \
    }                                                                         \
} while (0)

    f32x4 acc[4][4];
    #pragma unroll
    for (int i = 0; i < 4; ++i)
        #pragma unroll
        for (int j = 0; j < 4; ++j) acc[i][j] = (f32x4){0.f, 0.f, 0.f, 0.f};

    GLOAD(0);
    LWRITE(0, 0);
    GLOAD(1);
    asm volatile("s_waitcnt lgkmcnt(0)" ::: "memory");
    __builtin_amdgcn_s_barrier();

    #pragma unroll 1
    for (int ch = 0; ch < NCH; ++ch) {
        unsigned char* sA_ = &lds[ch & 1][0];
        unsigned char* sB_ = &lds[ch & 1][16384];
        #pragma unroll
        for (int ks = 0; ks < 2; ++ks) {
            const int kb = ks * 64 + lg * 16;   // 16B of k per lane-group
            half8 af[4], bf[4];
            #pragma unroll
            for (int i = 0; i < 4; ++i) {
                const int r_ = qr + i * 16 + li;
                af[i] = *(const half8*)(sA_ + r_ * 128 + (kb ^ ((r_ & 7) << 4)));
            }
            #pragma unroll
            for (int j = 0; j < 4; ++j) {
                const int c_ = qc + j * 16 + li;
                bf[j] = *(const half8*)(sB_ + c_ * 128 + (kb ^ ((c_ & 7) << 4)));
            }
            #pragma unroll
            for (int i = 0; i < 4; ++i)
                #pragma unroll
                for (int j = 0; j < 4; ++j)
                    acc[i][j] = __builtin_amdgcn_mfma_f32_16x16x32_f16(
                        af[i], bf[j], acc[i][j], 0, 0, 0);
        }
        if (ch == 15) {   // end of scaled phase: undo the 2^11 residual scaling
            #pragma unroll
            for (int i = 0; i < 4; ++i)
                #pragma unroll
                for (int j = 0; j < 4; ++j)
                    acc[i][j] *= (1.0f / 2048.0f);
        }
        if (ch + 1 < NCH) {
            LWRITE((ch + 1) & 1, ch + 1);   // other buffer: no race with readers
            if (ch + 2 < NCH) GLOAD(ch + 2);
        }
        asm volatile("s_waitcnt lgkmcnt(0)" ::: "memory");
        __builtin_amdgcn_s_barrier();
    }

    float cb[4];
    #pragma unroll
    for (int j = 0; j < 4; ++j) cb[j] = bias[n0 + qc + j * 16 + li];

    // LIF recurrence: both layers identical -> simulate once.
    // spk_t == reset_{t+1}; fold reset: mem = fma(beta, mem, sp ? c-1 : c)
    #pragma unroll
    for (int i = 0; i < 4; ++i) {
        int rsum[4] = {0, 0, 0, 0};
        #pragma unroll
        for (int j = 0; j < 4; ++j) {
            float c[4], c1[4], mem[4];
            int cnt[4];
            bool sp[4];
            #pragma unroll
            for (int r = 0; r < 4; ++r) {
                c[r]   = acc[i][j][r] + cb[j];
                c1[r]  = c[r] - 1.0f;
                mem[r] = 0.0f;
                cnt[r] = 0;
                sp[r]  = false;
            }
            #pragma unroll 1
            for (int tt = 0; tt < TSTEPS; ++tt) {
                #pragma unroll
                for (int r = 0; r < 4; ++r) {
                    mem[r] = fmaf(0.95f, mem[r], sp[r] ? c1[r] : c[r]);
                    sp[r]  = mem[r] > 1.0f;
                    cnt[r] += sp[r] ? 1 : 0;
                }
            }
            const int col = n0 + qc + j * 16 + li;
            #pragma unroll
            for (int r = 0; r < 4; ++r) {
                const int row = m0 + qr + i * 16 + lg * 4 + r;
                agg[(size_t)row * NDIM + col] = (float)cnt[r];
                rsum[r] += cnt[r];
            }
        }
        // tot: integer counts, exact in fp32, order-independent atomics
        #pragma unroll
        for (int r = 0; r < 4; ++r) {
            int s = rsum[r];
            s += __shfl_xor(s, 1);
            s += __shfl_xor(s, 2);
            s += __shfl_xor(s, 4);
            s += __shfl_xor(s, 8);
            if (li == 0)
                atomicAdd(&tot[m0 + qr + i * 16 + lg * 4 + r], 2.0f * (float)s);
        }
        __builtin_amdgcn_sched_barrier(0);  // sequence i-blocks: cap liveness
    }
}

extern "C" void kernel_launch(void* const* d_in, const int* in_sizes, int n_in,
                              void* d_out, int out_size, void* d_ws, size_t ws_size,
                              hipStream_t stream) {
    const float* x = (const float*)d_in[0];
    const float* W = (const float*)d_in[1];
    const float* b = (const float*)d_in[2];
    float* agg = (float*)d_out;
    float* tot = agg + (size_t)MDIM * NDIM;
    _Float16* B1 = (_Float16*)d_ws;                 // 1 MB
    _Float16* B2 = B1 + (size_t)KDIM * NDIM;        // 1 MB  (needs ws >= 2 MB)

    zero_tot_kernel<<<(MDIM + 255) / 256, 256, 0, stream>>>(tot);
    bsplit_kernel<<<(KDIM / 2) * NDIM / 256, 256, 0, stream>>>(W, B1, B2);
    snn_mfma_kernel<<<(MDIM / 128) * (NDIM / 128), 256, 0, stream>>>(
        x, B1, B2, b, agg, tot);
}

// Round 10
// 59.554 us; speedup vs baseline: 11.2023x; 1.6190x over previous
//
#include <hip/hip_runtime.h>
#include <stdint.h>

#define MDIM 4096
#define NDIM 1024
#define KDIM 512
#define TSTEPS 50
#define NCH 24            // 3 split-segments x 8 chunks of BK=64

typedef _Float16 half8 __attribute__((ext_vector_type(8)));
typedef float    f32x4 __attribute__((ext_vector_type(4)));

typedef const __attribute__((address_space(1))) void cgv_t;
typedef __attribute__((address_space(3))) void lv_t;

__device__ __forceinline__ void gload16(const void* g, void* s) {
    __builtin_amdgcn_global_load_lds((cgv_t*)g, (lv_t*)s, 16, 0, 0);
}

// ---- pre-kernels: split fp32 -> (f16, f16 residual*2048), row-image layout
// with the chunk-local XOR swizzle BAKED IN: half8 group k8 of row r lands at
// byte  (k8>>3)*128 + (((k8&7)*16) ^ ((r&7)<<4))  within the 1KB row image.
// GEMM then stages rows linearly via global_load_lds (dest linear = swizzled
// source) and applies the same XOR on ds_read (both-sides rule).

__global__ __launch_bounds__(256) void asplit_kernel(
    const float* __restrict__ A, _Float16* __restrict__ A1,
    _Float16* __restrict__ A2, float* __restrict__ tot)
{
    int idx = blockIdx.x * 256 + threadIdx.x;   // 262144 = 4096 rows x 64 k8
    if (idx < MDIM) tot[idx] = 0.0f;            // fused tot-zeroing
    int r = idx >> 6, k8 = idx & 63;
    float4 v0 = *(const float4*)(A + (size_t)r * KDIM + k8 * 8);
    float4 v1 = *(const float4*)(A + (size_t)r * KDIM + k8 * 8 + 4);
    float v[8] = {v0.x, v0.y, v0.z, v0.w, v1.x, v1.y, v1.z, v1.w};
    half8 h1, h2;
    #pragma unroll
    for (int e = 0; e < 8; ++e) {
        h1[e] = (_Float16)v[e];
        h2[e] = (_Float16)((v[e] - (float)h1[e]) * 2048.0f);
    }
    int off = r * 1024 + (k8 >> 3) * 128 + (((k8 & 7) * 16) ^ ((r & 7) << 4));
    *(half8*)((char*)A1 + off) = h1;
    *(half8*)((char*)A2 + off) = h2;
}

__global__ __launch_bounds__(256) void wsplit_kernel(
    const float* __restrict__ W, _Float16* __restrict__ B1, _Float16* __restrict__ B2)
{
    int idx = blockIdx.x * 256 + threadIdx.x;   // 65536 = 1024 n x 64 k8
    int n = idx >> 6, k8 = idx & 63;
    float v[8];
    #pragma unroll
    for (int e = 0; e < 8; ++e) v[e] = W[(size_t)(k8 * 8 + e) * NDIM + n];
    half8 h1, h2;
    #pragma unroll
    for (int e = 0; e < 8; ++e) {
        h1[e] = (_Float16)v[e];
        h2[e] = (_Float16)((v[e] - (float)h1[e]) * 2048.0f);
    }
    int off = n * 1024 + (k8 >> 3) * 128 + (((k8 & 7) * 16) ^ ((n & 7) << 4));
    *(half8*)((char*)B1 + off) = h1;
    *(half8*)((char*)B2 + off) = h2;
}

// Split-2 f16 MFMA GEMM + fused LIF. Segments (R9 numerics, bit-identical):
// ch 0-7: a2s*b1 ; ch 8-15: a1*b2s ; [acc *= 2^-11] ; ch 16-23: a1*b1.
// 64x64 tile, 256 thr (4 waves, each 32x32 = 2x2 frags of 16x16x32),
// 4 blocks/CU -> 4 waves/SIMD. Staging: pure global_load_lds from the
// pre-swizzled images; counted vmcnt(4); raw barriers (R7-proven pattern).
__global__ __launch_bounds__(256, 4) void snn_mfma_kernel(
    const _Float16* __restrict__ A1, const _Float16* __restrict__ A2,
    const _Float16* __restrict__ B1, const _Float16* __restrict__ B2,
    const float* __restrict__ bias, float* __restrict__ agg, float* __restrict__ tot)
{
    __shared__ __align__(16) unsigned char lds[2][16384];  // A 8KB | B 8KB per buf

    const int t  = threadIdx.x;
    const int l  = t & 63;
    const int w  = t >> 6;
    const int li = l & 15;
    const int lg = l >> 4;
    const int qr = (w >> 1) * 32;   // wave quadrant
    const int qc = (w & 1) * 32;

    // XCD swizzle (bijective, 1024 = 8 x 128): XCD x -> bm band of 8 (512 rows)
    const int swz = (blockIdx.x & 7) * 128 + (blockIdx.x >> 3);
    const int m0 = (swz >> 4) * 64;
    const int n0 = (swz & 15) * 64;

    // staging: per chunk 2 A-gload16 + 2 B-gload16 per thread; instr i_ covers
    // rows i_*32 + w*8 + (l>>3), bytes (l&7)*16 of the 128B chunk image.
    int aoff[2], boff[2], dstA[2], dstB[2];
    #pragma unroll
    for (int i_ = 0; i_ < 2; ++i_) {
        int rr  = i_ * 32 + w * 8 + (l >> 3);
        aoff[i_] = (m0 + rr) * 1024 + (l & 7) * 16;
        boff[i_] = (n0 + rr) * 1024 + (l & 7) * 16;
        dstA[i_] = (i_ * 32 + w * 8) * 128;
        dstB[i_] = 8192 + (i_ * 32 + w * 8) * 128;
    }

#define STAGE(buf, ch) do {                                                   \
    const int seg_ = (ch) >> 3, c_ = ((ch) & 7) * 128;                        \
    const char* As_ = (const char*)((seg_ == 0) ? A2 : A1);                   \
    const char* Bs_ = (const char*)((seg_ == 1) ? B2 : B1);                   \
    _Pragma("unroll") for (int i_ = 0; i_ < 2; ++i_)                          \
        gload16(As_ + aoff[i_] + c_, &lds[buf][dstA[i_]]);                    \
    _Pragma("unroll") for (int i_ = 0; i_ < 2; ++i_)                          \
        gload16(Bs_ + boff[i_] + c_, &lds[buf][dstB[i_]]);                    \
} while (0)

    f32x4 acc[2][2];
    #pragma unroll
    for (int i = 0; i < 2; ++i)
        #pragma unroll
        for (int j = 0; j < 2; ++j) acc[i][j] = (f32x4){0.f, 0.f, 0.f, 0.f};

    STAGE(0, 0);
    STAGE(1, 1);

    #pragma unroll 1
    for (int ch = 0; ch < NCH; ++ch) {
        if (ch < NCH - 1) asm volatile("s_waitcnt vmcnt(4)" ::: "memory");
        else              asm volatile("s_waitcnt vmcnt(0)" ::: "memory");
        __builtin_amdgcn_s_barrier();
        asm volatile("" ::: "memory");
        const unsigned char* sAb = &lds[ch & 1][0];
        const unsigned char* sBb = &lds[ch & 1][8192];
        #pragma unroll
        for (int ks = 0; ks < 2; ++ks) {
            const int kb = ks * 64 + lg * 16;
            half8 af[2], bf[2];
            #pragma unroll
            for (int i = 0; i < 2; ++i) {
                const int r_ = qr + i * 16 + li;
                af[i] = *(const half8*)(sAb + r_ * 128 + (kb ^ ((r_ & 7) << 4)));
            }
            #pragma unroll
            for (int j = 0; j < 2; ++j) {
                const int c_ = qc + j * 16 + li;
                bf[j] = *(const half8*)(sBb + c_ * 128 + (kb ^ ((c_ & 7) << 4)));
            }
            #pragma unroll
            for (int i = 0; i < 2; ++i)
                #pragma unroll
                for (int j = 0; j < 2; ++j)
                    acc[i][j] = __builtin_amdgcn_mfma_f32_16x16x32_f16(
                        af[i], bf[j], acc[i][j], 0, 0, 0);
        }
        if (ch == 15) {   // end of scaled phase: undo the 2^11 residual scaling
            #pragma unroll
            for (int i = 0; i < 2; ++i)
                #pragma unroll
                for (int j = 0; j < 2; ++j)
                    acc[i][j] *= (1.0f / 2048.0f);
        }
        __builtin_amdgcn_s_barrier();
        asm volatile("" ::: "memory");
        if (ch + 2 < NCH) STAGE(ch & 1, ch + 2);
    }

    float cb[2];
    #pragma unroll
    for (int j = 0; j < 2; ++j) cb[j] = bias[n0 + qc + j * 16 + li];

    // LIF recurrence: both layers identical -> simulate once.
    // spk_t == reset_{t+1}; fold reset: mem = fma(beta, mem, sp ? c-1 : c)
    #pragma unroll
    for (int i = 0; i < 2; ++i) {
        int rsum[4] = {0, 0, 0, 0};
        #pragma unroll
        for (int j = 0; j < 2; ++j) {
            float c[4], c1[4], mem[4];
            int cnt[4];
            bool sp[4];
            #pragma unroll
            for (int r = 0; r < 4; ++r) {
                c[r]   = acc[i][j][r] + cb[j];
                c1[r]  = c[r] - 1.0f;
                mem[r] = 0.0f;
                cnt[r] = 0;
                sp[r]  = false;
            }
            #pragma unroll 1
            for (int tt = 0; tt < TSTEPS; ++tt) {
                #pragma unroll
                for (int r = 0; r < 4; ++r) {
                    mem[r] = fmaf(0.95f, mem[r], sp[r] ? c1[r] : c[r]);
                    sp[r]  = mem[r] > 1.0f;
                    cnt[r] += sp[r] ? 1 : 0;
                }
            }
            const int col = n0 + qc + j * 16 + li;
            #pragma unroll
            for (int r = 0; r < 4; ++r) {
                const int row = m0 + qr + i * 16 + lg * 4 + r;
                agg[(size_t)row * NDIM + col] = (float)cnt[r];
                rsum[r] += cnt[r];
            }
        }
        // tot: integer counts, exact in fp32, order-independent atomics
        #pragma unroll
        for (int r = 0; r < 4; ++r) {
            int s = rsum[r];
            s += __shfl_xor(s, 1);
            s += __shfl_xor(s, 2);
            s += __shfl_xor(s, 4);
            s += __shfl_xor(s, 8);
            if (li == 0)
                atomicAdd(&tot[m0 + qr + i * 16 + lg * 4 + r], 2.0f * (float)s);
        }
        __builtin_amdgcn_sched_barrier(0);  // sequence i-blocks: cap liveness
    }
}

extern "C" void kernel_launch(void* const* d_in, const int* in_sizes, int n_in,
                              void* d_out, int out_size, void* d_ws, size_t ws_size,
                              hipStream_t stream) {
    const float* x = (const float*)d_in[0];
    const float* W = (const float*)d_in[1];
    const float* b = (const float*)d_in[2];
    float* agg = (float*)d_out;
    float* tot = agg + (size_t)MDIM * NDIM;

    char* ws = (char*)d_ws;                       // needs ws_size >= 10 MB
    _Float16* A1 = (_Float16*)(ws);               // 4 MB
    _Float16* A2 = (_Float16*)(ws + (4 << 20));   // 4 MB
    _Float16* B1 = (_Float16*)(ws + (8 << 20));   // 1 MB
    _Float16* B2 = (_Float16*)(ws + (9 << 20));   // 1 MB

    asplit_kernel<<<(MDIM * KDIM / 8) / 256, 256, 0, stream>>>(x, A1, A2, tot);
    wsplit_kernel<<<(NDIM * KDIM / 8) / 256, 256, 0, stream>>>(W, B1, B2);
    snn_mfma_kernel<<<(MDIM / 64) * (NDIM / 64), 256, 0, stream>>>(
        A1, A2, B1, B2, b, agg, tot);
}